// Round 7
// baseline (186.113 us; speedup 1.0000x reference)
//
#include <hip/hip_runtime.h>
#include <hip/hip_cooperative_groups.h>
#include <stdint.h>

namespace cg = cooperative_groups;

#define BATCH 16
#define NPIX 200704   // 448*448
#define EPS 1e-6f
#define FW 256        // fine-grid size; FW*FW = 65536 = 4 x 16384-word windows
#define GRID 256
#define TPB 256

// K(j,g) = 1 / (1 + ((c_j - b_g)/sigma)^2), c_j=(j+0.5)/FW, b_g=g/63, 1/sigma=50
__device__ __forceinline__ float kval(int j, int g) {
  float d = (((float)j + 0.5f) * (1.0f / (float)FW) - (float)g * (1.0f / 63.0f)) * 50.0f;
  return 1.0f / (1.0f + d * d);
}

__global__ __launch_bounds__(TPB) void fused_all(
    const float* __restrict__ x,
    unsigned short* __restrict__ ids,
    float* __restrict__ Hf,
    float* __restrict__ Pp,
    float* __restrict__ psum,
    float* __restrict__ out)
{
  cg::grid_group grid = cg::this_grid();
  __shared__ __align__(16) unsigned char smem[65536];
  const int bid = blockIdx.x;
  const int tid = threadIdx.x;
  const int xcd = bid & 7;   // all phases pin batch b to XCD b%8 (L2 locality)

  // ---------------- P1: chroma -> u16 fine-grid id (all 256 blocks) ----------------
  {
    int sub = bid >> 3;                       // 0..31 within xcd group
    for (int k = sub * TPB + tid; k < 2 * (NPIX / 8); k += 32 * TPB) {
      int bh = k / (NPIX / 8);
      int q8 = k - bh * (NPIX / 8);           // octet index within batch
      int b = xcd + 8 * bh;
      const float* xb = x + (size_t)b * 3 * NPIX;
      const float4* R  = (const float4*)xb;
      const float4* G  = (const float4*)(xb + NPIX);
      const float4* Bl = (const float4*)(xb + 2 * NPIX);
      float4 r0 = R[2 * q8], r1 = R[2 * q8 + 1];
      float4 g0 = G[2 * q8], g1 = G[2 * q8 + 1];
      float4 b0 = Bl[2 * q8], b1 = Bl[2 * q8 + 1];
      float rr[8] = {r0.x, r0.y, r0.z, r0.w, r1.x, r1.y, r1.z, r1.w};
      float gg[8] = {g0.x, g0.y, g0.z, g0.w, g1.x, g1.y, g1.z, g1.w};
      float bb[8] = {b0.x, b0.y, b0.z, b0.w, b1.x, b1.y, b1.z, b1.w};
      unsigned int u[4];
#pragma unroll
      for (int t2 = 0; t2 < 4; t2++) {
        unsigned int id2[2];
#pragma unroll
        for (int h = 0; h < 2; h++) {
          int t3 = t2 * 2 + h;
          float r  = fminf(fmaxf(rr[t3], 0.0f), 1.0f);
          float g  = fminf(fmaxf(gg[t3], 0.0f), 1.0f);
          float bl = fminf(fmaxf(bb[t3], 0.0f), 1.0f);
          float inv = 1.0f / (r + g + bl + EPS);
          int i = min((int)(r * inv * (float)FW), FW - 1);
          int j = min((int)(g * inv * (float)FW), FW - 1);
          id2[h] = (unsigned int)(i * FW + j);
        }
        u[t2] = id2[0] | (id2[1] << 16);
      }
      ((uint4*)(ids + (size_t)b * NPIX))[q8] = make_uint4(u[0], u[1], u[2], u[3]);
    }
  }
  grid.sync();

  // ---------------- P2: per-(batch,window) LDS histogram (64 blocks) ----------------
  if (bid < BATCH * 4) {
    unsigned int* sh = (unsigned int*)smem;
    int t0 = bid >> 3;                        // 0..7
    unsigned int w = (unsigned int)(t0 & 3);
    int b = xcd + 8 * (t0 >> 2);
    for (int t = tid; t < 16384; t += TPB) sh[t] = 0u;
    __syncthreads();
    const uint4* idv = (const uint4*)(ids + (size_t)b * NPIX);
    for (int t = tid; t < NPIX / 8; t += TPB) {
      uint4 v = idv[t];
      unsigned int a;
      a = v.x & 0xFFFFu; if ((a >> 14) == w) atomicAdd(&sh[a & 16383u], 1u);
      a = v.x >> 16;     if ((a >> 14) == w) atomicAdd(&sh[a & 16383u], 1u);
      a = v.y & 0xFFFFu; if ((a >> 14) == w) atomicAdd(&sh[a & 16383u], 1u);
      a = v.y >> 16;     if ((a >> 14) == w) atomicAdd(&sh[a & 16383u], 1u);
      a = v.z & 0xFFFFu; if ((a >> 14) == w) atomicAdd(&sh[a & 16383u], 1u);
      a = v.z >> 16;     if ((a >> 14) == w) atomicAdd(&sh[a & 16383u], 1u);
      a = v.w & 0xFFFFu; if ((a >> 14) == w) atomicAdd(&sh[a & 16383u], 1u);
      a = v.w >> 16;     if ((a >> 14) == w) atomicAdd(&sh[a & 16383u], 1u);
    }
    __syncthreads();
    float4* dst = (float4*)(Hf + (size_t)b * (FW * FW) + (size_t)w * 16384);
    for (int t = tid; t < 4096; t += TPB) {
      uint4 v = ((const uint4*)sh)[t];
      dst[t] = make_float4((float)v.x, (float)v.y, (float)v.z, (float)v.w);
    }
  }
  grid.sync();

  // ---------------- P3: fused B+C (all 256 blocks, one task each) ----------------
  {
    float (*sH)[68] = (float (*)[68])smem;                 // 64x68 padded
    float (*sK)[64] = (float (*)[64])(smem + 64 * 68 * 4); // 64x64
    int t0 = bid >> 3;            // 0..31
    int q = t0 & 3;
    int itile = (t0 >> 2) & 3;
    int b = xcd + 8 * (t0 >> 4);
    int gq4 = (tid & 15) * 4;
    int iq4 = (tid >> 4) * 4;     // i-quad main loop; r-quad epilogue
    int j0 = q * 64;
    const float* Hbase = Hf + (size_t)b * (FW * FW) + (size_t)(itile * 64) * FW;
    float acc[4][4];
#pragma unroll
    for (int a2 = 0; a2 < 4; a2++)
#pragma unroll
      for (int c = 0; c < 4; c++) acc[a2][c] = 0.0f;

#pragma unroll
    for (int rep = 0; rep < 4; rep++) {       // H tile 64x64
      int idx = rep * 256 + tid;
      int ii = idx >> 4, jj4 = (idx & 15) * 4;
      *(float4*)&sH[ii][jj4] = *(const float4*)&Hbase[(size_t)ii * FW + j0 + jj4];
    }
#pragma unroll
    for (int rep = 0; rep < 4; rep++) {       // K tile computed in-place
      int idx = rep * 256 + tid;
      int jr = idx >> 4, g4 = (idx & 15) * 4;
      sK[jr][g4 + 0] = kval(j0 + jr, g4 + 0);
      sK[jr][g4 + 1] = kval(j0 + jr, g4 + 1);
      sK[jr][g4 + 2] = kval(j0 + jr, g4 + 2);
      sK[jr][g4 + 3] = kval(j0 + jr, g4 + 3);
    }
    __syncthreads();
#pragma unroll 4
    for (int tt = 0; tt < 16; tt++) {         // 4 j per step, all b128
      float hh[4][4], kk[4][4];
#pragma unroll
      for (int di = 0; di < 4; di++) {
        float4 v = *(const float4*)&sH[iq4 + di][tt * 4];
        hh[di][0] = v.x; hh[di][1] = v.y; hh[di][2] = v.z; hh[di][3] = v.w;
      }
#pragma unroll
      for (int p = 0; p < 4; p++) {
        float4 v = *(const float4*)&sK[tt * 4 + p][gq4];
        kk[p][0] = v.x; kk[p][1] = v.y; kk[p][2] = v.z; kk[p][3] = v.w;
      }
#pragma unroll
      for (int p = 0; p < 4; p++)
#pragma unroll
        for (int di = 0; di < 4; di++)
#pragma unroll
          for (int dg = 0; dg < 4; dg++)
            acc[di][dg] = fmaf(hh[di][p], kk[p][dg], acc[di][dg]);
    }
    __syncthreads();
    // epilogue: P_slice = K_C^T * M_tile (on-chip)
#pragma unroll
    for (int di = 0; di < 4; di++) {
      float4 v = make_float4(acc[di][0], acc[di][1], acc[di][2], acc[di][3]);
      *(float4*)&sK[iq4 + di][gq4] = v;       // M tile rows=i, cols=g
    }
    int i0f = itile * 64;
#pragma unroll
    for (int rep = 0; rep < 4; rep++) {       // K_C rows=i, cols=r
      int idx = rep * 256 + tid;
      int ii = idx >> 4, r4b = (idx & 15) * 4;
      sH[ii][r4b + 0] = kval(i0f + ii, r4b + 0);
      sH[ii][r4b + 1] = kval(i0f + ii, r4b + 1);
      sH[ii][r4b + 2] = kval(i0f + ii, r4b + 2);
      sH[ii][r4b + 3] = kval(i0f + ii, r4b + 3);
    }
    __syncthreads();
    float acc2[4][4];
#pragma unroll
    for (int a2 = 0; a2 < 4; a2++)
#pragma unroll
      for (int c = 0; c < 4; c++) acc2[a2][c] = 0.0f;
#pragma unroll 8
    for (int ip = 0; ip < 64; ip++) {
      float4 kc = *(const float4*)&sH[ip][iq4];
      float4 mm = *(const float4*)&sK[ip][gq4];
      float kk2[4] = {kc.x, kc.y, kc.z, kc.w};
      float mv[4]  = {mm.x, mm.y, mm.z, mm.w};
#pragma unroll
      for (int dr = 0; dr < 4; dr++)
#pragma unroll
        for (int dg = 0; dg < 4; dg++)
          acc2[dr][dg] = fmaf(kk2[dr], mv[dg], acc2[dr][dg]);
    }
    float* Pb = Pp + ((size_t)b * 16 + (size_t)(itile * 4 + q)) * 4096;
#pragma unroll
    for (int dr = 0; dr < 4; dr++) {
      float4 v = make_float4(acc2[dr][0], acc2[dr][1], acc2[dr][2], acc2[dr][3]);
      *(float4*)&Pb[(size_t)(iq4 + dr) * 64 + gq4] = v;
    }
  }
  grid.sync();

  // ---------------- P4: slice reduce (s stays in register), psum ----------------
  float sv;
  int bG, rgG;
  {
    int t0 = bid >> 3;            // 0..31
    int sl = t0 & 15;
    int b = xcd + 8 * (t0 >> 4);
    int rg = sl * 256 + tid;
    const float* Pb = Pp + (size_t)b * 16 * 4096;
    float s = 0.0f;
#pragma unroll
    for (int c = 0; c < 16; c++) s += Pb[(size_t)c * 4096 + rg];
    float* red = (float*)smem;
    red[tid] = s;
    __syncthreads();
    for (int st = 128; st > 0; st >>= 1) {
      if (tid < st) red[tid] += red[tid + st];
      __syncthreads();
    }
    if (tid == 0) psum[b * 16 + sl] = red[0];
    sv = s; bG = b; rgG = rg;
  }
  grid.sync();

  // ---------------- P5: normalize + store ----------------
  {
    const float* ps = psum + bG * 16;
    float tot = 0.0f;
#pragma unroll
    for (int c = 0; c < 16; c++) tot += ps[c];
    float inv = 1.0f / (tot + EPS);
    out[(size_t)bG * 4096 + rgG] = sv * inv;
  }
}

extern "C" void kernel_launch(void* const* d_in, const int* in_sizes, int n_in,
                              void* d_out, int out_size, void* d_ws, size_t ws_size,
                              hipStream_t stream) {
  const float* x = (const float*)d_in[0];
  float* out = (float*)d_out;

  char* p = (char*)d_ws;
  unsigned short* ids = (unsigned short*)p; p += (size_t)BATCH * NPIX * 2;   // 6.4 MB
  float* Hf = (float*)p;                    p += (size_t)BATCH * FW * FW * 4; // 4 MB
  float* Pp = (float*)p;                    p += (size_t)BATCH * 16 * 4096 * 4; // 4 MB
  float* psum = (float*)p;

  void* args[] = {(void*)&x, (void*)&ids, (void*)&Hf, (void*)&Pp,
                  (void*)&psum, (void*)&out};
  hipLaunchCooperativeKernel((void*)fused_all, dim3(GRID), dim3(TPB),
                             args, 0, stream);
}

// Round 8
// 59.877 us; speedup vs baseline: 3.1082x; 3.1082x over previous
//
#include <hip/hip_runtime.h>
#include <stdint.h>

#define BATCH 16
#define NPIX 200704      // 448*448
#define NQF4 12544       // float4 groups per pixel-quarter (50176 px / 4)
#define EPS 1e-6f
#define FW 256           // fine grid; id = i*256+j; window = i>>6 (4 windows of 64 rows)

// K(c,g) = 1 / (1 + ((cc - b_g)/sigma)^2), cc=(c+0.5)/FW, b_g=g/63, 1/sigma=50
__device__ __forceinline__ float kval(int c, int g) {
  float d = (((float)c + 0.5f) * (1.0f / (float)FW) - (float)g * (1.0f / 63.0f)) * 50.0f;
  return 1.0f / (1.0f + d * d);
}

// ---------------- K1: direct chroma histogram, per (batch, window, quarter) ----------------
// Hq[b][w][qt][16384]: float counts of window w (rows 64w..64w+63) from pixel-quarter qt.
__global__ __launch_bounds__(1024) void hist_direct(const float* __restrict__ x,
                                                    float* __restrict__ Hq,
                                                    unsigned int* __restrict__ counter) {
  __shared__ unsigned int sh[16384];
  const int bid = blockIdx.x;
  const int tid = threadIdx.x;
  const int xcd = bid & 7;           // batch pinned to XCD b%8
  const int t0 = bid >> 3;           // 0..31
  const unsigned int w = (unsigned int)(t0 & 3);
  const int qt = (t0 >> 2) & 3;
  const int b = xcd + 8 * (t0 >> 4);

  if (bid < BATCH && tid == 0) counter[bid] = 0u;   // reset tickets every call

  for (int t = tid; t < 16384; t += 1024) sh[t] = 0u;
  __syncthreads();

  const float* xb = x + (size_t)b * 3 * NPIX;
  const float4* R  = (const float4*)xb + qt * NQF4;
  const float4* G  = (const float4*)(xb + NPIX) + qt * NQF4;
  const float4* Bl = (const float4*)(xb + 2 * NPIX) + qt * NQF4;

  for (int t = tid; t < NQF4; t += 1024) {
    float4 rv = R[t], gv = G[t], bv = Bl[t];
    float rr[4] = {rv.x, rv.y, rv.z, rv.w};
    float gg[4] = {gv.x, gv.y, gv.z, gv.w};
    float bb[4] = {bv.x, bv.y, bv.z, bv.w};
#pragma unroll
    for (int c = 0; c < 4; c++) {
      float r  = fminf(fmaxf(rr[c], 0.0f), 1.0f);
      float g  = fminf(fmaxf(gg[c], 0.0f), 1.0f);
      float bl = fminf(fmaxf(bb[c], 0.0f), 1.0f);
      float inv = 1.0f / (r + g + bl + EPS);
      int i = min((int)(r * inv * (float)FW), FW - 1);
      int j = min((int)(g * inv * (float)FW), FW - 1);
      unsigned int id = (unsigned int)((i << 8) | j);
      if ((id >> 14) == w) atomicAdd(&sh[id & 16383u], 1u);
    }
  }
  __syncthreads();

  float4* dst = (float4*)(Hq + (((size_t)b * 4 + w) * 4 + qt) * 16384);
  for (int t = tid; t < 4096; t += 1024) {
    uint4 v = ((const uint4*)sh)[t];
    dst[t] = make_float4((float)v.x, (float)v.y, (float)v.z, (float)v.w);
  }
}

// ---------------- K2: fused M-GEMM + K^T epilogue + ticket tail ----------------
// block (b, itile, jq): M[i][g] = sum_{j in jq-chunk} H[it*64+i][j]*K[j][g]  (i,g in 64x64)
// P[b][it*4+jq][r][g]  = sum_i K(it*64+i, r) * M[i][g];  psumC = slice total.
// Last-of-16 block per batch: out = (sum_slices P) / (sum psumC + EPS).
__global__ __launch_bounds__(256) void stageBC_tail(const float* __restrict__ Hq,
                                                    float* __restrict__ Pp,
                                                    float* __restrict__ psumC,
                                                    unsigned int* __restrict__ counter,
                                                    float* __restrict__ out) {
  __shared__ float sH[64][68];   // H tile (padded); K_C in epilogue
  __shared__ float sK[64][64];   // K tile; M tile in epilogue
  __shared__ float sred[256];
  __shared__ int s_last;
  const int bid = blockIdx.x;
  const int tid = threadIdx.x;
  const int xcd = bid & 7;
  const int t0 = bid >> 3;       // 0..31
  const int jq = t0 & 3;
  const int it = (t0 >> 2) & 3;
  const int b = xcd + 8 * (t0 >> 4);
  const int gq4 = (tid & 15) * 4;
  const int iq4 = (tid >> 4) * 4;

  // ---- stage H tile: sum 4 quarter-hists of window 'it', cols [64*jq .. +64) ----
  const float4* Hw = (const float4*)(Hq + ((size_t)b * 4 + it) * 4 * 16384);
#pragma unroll
  for (int rep = 0; rep < 4; rep++) {
    int idx = rep * 256 + tid;
    int ii = idx >> 4, c = idx & 15;
    int f4i = ii * 64 + jq * 16 + c;            // float4 index within one quarter-hist
    float4 a0 = Hw[f4i];
    float4 a1 = Hw[4096 + f4i];
    float4 a2 = Hw[8192 + f4i];
    float4 a3 = Hw[12288 + f4i];
    float4 s = make_float4(a0.x + a1.x + a2.x + a3.x, a0.y + a1.y + a2.y + a3.y,
                           a0.z + a1.z + a2.z + a3.z, a0.w + a1.w + a2.w + a3.w);
    *(float4*)&sH[ii][c * 4] = s;
  }
  // ---- K tile for j-chunk ----
  int j0 = jq * 64;
#pragma unroll
  for (int rep = 0; rep < 4; rep++) {
    int idx = rep * 256 + tid;
    int jr = idx >> 4, g4 = (idx & 15) * 4;
    sK[jr][g4 + 0] = kval(j0 + jr, g4 + 0);
    sK[jr][g4 + 1] = kval(j0 + jr, g4 + 1);
    sK[jr][g4 + 2] = kval(j0 + jr, g4 + 2);
    sK[jr][g4 + 3] = kval(j0 + jr, g4 + 3);
  }
  __syncthreads();

  // ---- M-phase: acc[4][4] over 64 j ----
  float acc[4][4];
#pragma unroll
  for (int a = 0; a < 4; a++)
#pragma unroll
    for (int c = 0; c < 4; c++) acc[a][c] = 0.0f;
#pragma unroll 4
  for (int tt = 0; tt < 16; tt++) {
    float hh[4][4], kk[4][4];
#pragma unroll
    for (int di = 0; di < 4; di++) {
      float4 v = *(const float4*)&sH[iq4 + di][tt * 4];
      hh[di][0] = v.x; hh[di][1] = v.y; hh[di][2] = v.z; hh[di][3] = v.w;
    }
#pragma unroll
    for (int p = 0; p < 4; p++) {
      float4 v = *(const float4*)&sK[tt * 4 + p][gq4];
      kk[p][0] = v.x; kk[p][1] = v.y; kk[p][2] = v.z; kk[p][3] = v.w;
    }
#pragma unroll
    for (int p = 0; p < 4; p++)
#pragma unroll
      for (int di = 0; di < 4; di++)
#pragma unroll
        for (int dg = 0; dg < 4; dg++)
          acc[di][dg] = fmaf(hh[di][p], kk[p][dg], acc[di][dg]);
  }
  __syncthreads();

  // ---- epilogue: P_slice = K_C^T * M (on-chip) ----
#pragma unroll
  for (int di = 0; di < 4; di++) {
    float4 v = make_float4(acc[di][0], acc[di][1], acc[di][2], acc[di][3]);
    *(float4*)&sK[iq4 + di][gq4] = v;           // M tile: rows=i, cols=g
  }
  int i0f = it * 64;
#pragma unroll
  for (int rep = 0; rep < 4; rep++) {           // K_C: rows=i, cols=r
    int idx = rep * 256 + tid;
    int ii = idx >> 4, r4b = (idx & 15) * 4;
    sH[ii][r4b + 0] = kval(i0f + ii, r4b + 0);
    sH[ii][r4b + 1] = kval(i0f + ii, r4b + 1);
    sH[ii][r4b + 2] = kval(i0f + ii, r4b + 2);
    sH[ii][r4b + 3] = kval(i0f + ii, r4b + 3);
  }
  __syncthreads();
  float acc2[4][4];
#pragma unroll
  for (int a = 0; a < 4; a++)
#pragma unroll
    for (int c = 0; c < 4; c++) acc2[a][c] = 0.0f;
#pragma unroll 8
  for (int ip = 0; ip < 64; ip++) {
    float4 kc = *(const float4*)&sH[ip][iq4];   // r-quad
    float4 mm = *(const float4*)&sK[ip][gq4];
    float kk2[4] = {kc.x, kc.y, kc.z, kc.w};
    float mv[4]  = {mm.x, mm.y, mm.z, mm.w};
#pragma unroll
    for (int dr = 0; dr < 4; dr++)
#pragma unroll
      for (int dg = 0; dg < 4; dg++)
        acc2[dr][dg] = fmaf(kk2[dr], mv[dg], acc2[dr][dg]);
  }

  // ---- slice sum (fixed order) + P write ----
  int slice = it * 4 + jq;
  float ps = 0.0f;
#pragma unroll
  for (int dr = 0; dr < 4; dr++)
#pragma unroll
    for (int dg = 0; dg < 4; dg++) ps += acc2[dr][dg];
  sred[tid] = ps;
  __syncthreads();
  for (int st = 128; st > 0; st >>= 1) {
    if (tid < st) sred[tid] += sred[tid + st];
    __syncthreads();
  }
  if (tid == 0) psumC[b * 16 + slice] = sred[0];

  float* Pb = Pp + ((size_t)b * 16 + slice) * 4096;
#pragma unroll
  for (int dr = 0; dr < 4; dr++) {
    float4 v = make_float4(acc2[dr][0], acc2[dr][1], acc2[dr][2], acc2[dr][3]);
    *(float4*)&Pb[(size_t)(iq4 + dr) * 64 + gq4] = v;
  }

  // ---- ticket: last of the batch's 16 blocks finishes the batch ----
  __threadfence();
  if (tid == 0) {
    unsigned int old = atomicAdd(&counter[b], 1u);
    s_last = (old == 15u) ? 1 : 0;
  }
  __syncthreads();
  if (!s_last) return;
  __threadfence();

  const float* PbAll = Pp + (size_t)b * 16 * 4096;
  const float* pc = psumC + b * 16;
  float tot = 0.0f;
#pragma unroll
  for (int c = 0; c < 16; c++) tot += pc[c];
  float inv = 1.0f / (tot + EPS);
#pragma unroll
  for (int t2 = 0; t2 < 16; t2++) {
    int rg = t2 * 256 + tid;
    float s = 0.0f;
#pragma unroll
    for (int c = 0; c < 16; c++) s += PbAll[(size_t)c * 4096 + rg];
    out[(size_t)b * 4096 + rg] = s * inv;
  }
}

extern "C" void kernel_launch(void* const* d_in, const int* in_sizes, int n_in,
                              void* d_out, int out_size, void* d_ws, size_t ws_size,
                              hipStream_t stream) {
  const float* x = (const float*)d_in[0];
  float* out = (float*)d_out;

  char* p = (char*)d_ws;
  float* Hq = (float*)p;                 p += (size_t)BATCH * 4 * 4 * 16384 * 4;  // 16 MB
  float* Pp = (float*)p;                 p += (size_t)BATCH * 16 * 4096 * 4;      // 4 MB
  float* psumC = (float*)p;              p += (size_t)BATCH * 16 * 4;
  unsigned int* counter = (unsigned int*)p;

  hist_direct<<<256, 1024, 0, stream>>>(x, Hq, counter);
  stageBC_tail<<<256, 256, 0, stream>>>(Hq, Pp, psumC, counter, out);
}

// Round 9
// 35.208 us; speedup vs baseline: 5.2861x; 1.7007x over previous
//
#include <hip/hip_runtime.h>
#include <stdint.h>

#define BATCH 16
#define NPIX 200704      // 448*448
#define NQF4 12544       // float4 groups per pixel-quarter (50176 px / 4)
#define EPS 1e-6f
#define FW 256           // fine grid; id = i*256+j; window = i>>6 (4 windows of 64 rows)

// K(c,g) = 1 / (1 + ((cc - b_g)/sigma)^2), cc=(c+0.5)/FW, b_g=g/63, 1/sigma=50
__device__ __forceinline__ float kval(int c, int g) {
  float d = (((float)c + 0.5f) * (1.0f / (float)FW) - (float)g * (1.0f / 63.0f)) * 50.0f;
  return 1.0f / (1.0f + d * d);
}

// ---------------- K1: direct chroma histogram, per (batch, window, quarter) ----------------
// Hq[b][w][qt][16384]: float counts of window w (rows 64w..64w+63) from pixel-quarter qt.
__global__ __launch_bounds__(1024) void hist_direct(const float* __restrict__ x,
                                                    float* __restrict__ Hq) {
  __shared__ unsigned int sh[16384];
  const int bid = blockIdx.x;
  const int tid = threadIdx.x;
  const int xcd = bid & 7;           // batch pinned to XCD b%8
  const int t0 = bid >> 3;           // 0..31
  const unsigned int w = (unsigned int)(t0 & 3);
  const int qt = (t0 >> 2) & 3;
  const int b = xcd + 8 * (t0 >> 4);

  for (int t = tid; t < 16384; t += 1024) sh[t] = 0u;
  __syncthreads();

  const float* xb = x + (size_t)b * 3 * NPIX;
  const float4* R  = (const float4*)xb + qt * NQF4;
  const float4* G  = (const float4*)(xb + NPIX) + qt * NQF4;
  const float4* Bl = (const float4*)(xb + 2 * NPIX) + qt * NQF4;

  for (int t = tid; t < NQF4; t += 1024) {
    float4 rv = R[t], gv = G[t], bv = Bl[t];
    float rr[4] = {rv.x, rv.y, rv.z, rv.w};
    float gg[4] = {gv.x, gv.y, gv.z, gv.w};
    float bb[4] = {bv.x, bv.y, bv.z, bv.w};
#pragma unroll
    for (int c = 0; c < 4; c++) {
      float r  = fminf(fmaxf(rr[c], 0.0f), 1.0f);
      float g  = fminf(fmaxf(gg[c], 0.0f), 1.0f);
      float bl = fminf(fmaxf(bb[c], 0.0f), 1.0f);
      float inv = 1.0f / (r + g + bl + EPS);
      int i = min((int)(r * inv * (float)FW), FW - 1);
      int j = min((int)(g * inv * (float)FW), FW - 1);
      unsigned int id = (unsigned int)((i << 8) | j);
      if ((id >> 14) == w) atomicAdd(&sh[id & 16383u], 1u);
    }
  }
  __syncthreads();

  float4* dst = (float4*)(Hq + (((size_t)b * 4 + w) * 4 + qt) * 16384);
  for (int t = tid; t < 4096; t += 1024) {
    uint4 v = ((const uint4*)sh)[t];
    dst[t] = make_float4((float)v.x, (float)v.y, (float)v.z, (float)v.w);
  }
}

// ---------------- K2: fused M-GEMM + K^T epilogue ----------------
// block (b, it, jq): M[i][g] = sum_{j in jq-chunk} H[it*64+i][j]*K[j][g]  (i,g in 64x64)
// P[b][it*4+jq][r][g]  = sum_i K(it*64+i, r) * M[i][g];  psumC[b][slice] = slice total.
__global__ __launch_bounds__(256) void stageBC(const float* __restrict__ Hq,
                                               float* __restrict__ Pp,
                                               float* __restrict__ psumC) {
  __shared__ float sH[64][68];   // H tile (padded); K_C in epilogue
  __shared__ float sK[64][64];   // K tile; M tile in epilogue
  __shared__ float sred[256];
  const int bid = blockIdx.x;
  const int tid = threadIdx.x;
  const int xcd = bid & 7;
  const int t0 = bid >> 3;       // 0..31
  const int jq = t0 & 3;
  const int it = (t0 >> 2) & 3;
  const int b = xcd + 8 * (t0 >> 4);
  const int gq4 = (tid & 15) * 4;
  const int iq4 = (tid >> 4) * 4;

  // ---- stage H tile: sum 4 quarter-hists of window 'it', cols [64*jq .. +64) ----
  const float4* Hw = (const float4*)(Hq + ((size_t)b * 4 + it) * 4 * 16384);
#pragma unroll
  for (int rep = 0; rep < 4; rep++) {
    int idx = rep * 256 + tid;
    int ii = idx >> 4, c = idx & 15;
    int f4i = ii * 64 + jq * 16 + c;            // float4 index within one quarter-hist
    float4 a0 = Hw[f4i];
    float4 a1 = Hw[4096 + f4i];
    float4 a2 = Hw[8192 + f4i];
    float4 a3 = Hw[12288 + f4i];
    float4 s = make_float4(a0.x + a1.x + a2.x + a3.x, a0.y + a1.y + a2.y + a3.y,
                           a0.z + a1.z + a2.z + a3.z, a0.w + a1.w + a2.w + a3.w);
    *(float4*)&sH[ii][c * 4] = s;
  }
  // ---- K tile for j-chunk ----
  int j0 = jq * 64;
#pragma unroll
  for (int rep = 0; rep < 4; rep++) {
    int idx = rep * 256 + tid;
    int jr = idx >> 4, g4 = (idx & 15) * 4;
    sK[jr][g4 + 0] = kval(j0 + jr, g4 + 0);
    sK[jr][g4 + 1] = kval(j0 + jr, g4 + 1);
    sK[jr][g4 + 2] = kval(j0 + jr, g4 + 2);
    sK[jr][g4 + 3] = kval(j0 + jr, g4 + 3);
  }
  __syncthreads();

  // ---- M-phase: acc[4][4] over 64 j ----
  float acc[4][4];
#pragma unroll
  for (int a = 0; a < 4; a++)
#pragma unroll
    for (int c = 0; c < 4; c++) acc[a][c] = 0.0f;
#pragma unroll 4
  for (int tt = 0; tt < 16; tt++) {
    float hh[4][4], kk[4][4];
#pragma unroll
    for (int di = 0; di < 4; di++) {
      float4 v = *(const float4*)&sH[iq4 + di][tt * 4];
      hh[di][0] = v.x; hh[di][1] = v.y; hh[di][2] = v.z; hh[di][3] = v.w;
    }
#pragma unroll
    for (int p = 0; p < 4; p++) {
      float4 v = *(const float4*)&sK[tt * 4 + p][gq4];
      kk[p][0] = v.x; kk[p][1] = v.y; kk[p][2] = v.z; kk[p][3] = v.w;
    }
#pragma unroll
    for (int p = 0; p < 4; p++)
#pragma unroll
      for (int di = 0; di < 4; di++)
#pragma unroll
        for (int dg = 0; dg < 4; dg++)
          acc[di][dg] = fmaf(hh[di][p], kk[p][dg], acc[di][dg]);
  }
  __syncthreads();

  // ---- epilogue: P_slice = K_C^T * M (on-chip) ----
#pragma unroll
  for (int di = 0; di < 4; di++) {
    float4 v = make_float4(acc[di][0], acc[di][1], acc[di][2], acc[di][3]);
    *(float4*)&sK[iq4 + di][gq4] = v;           // M tile: rows=i, cols=g
  }
  int i0f = it * 64;
#pragma unroll
  for (int rep = 0; rep < 4; rep++) {           // K_C: rows=i, cols=r
    int idx = rep * 256 + tid;
    int ii = idx >> 4, r4b = (idx & 15) * 4;
    sH[ii][r4b + 0] = kval(i0f + ii, r4b + 0);
    sH[ii][r4b + 1] = kval(i0f + ii, r4b + 1);
    sH[ii][r4b + 2] = kval(i0f + ii, r4b + 2);
    sH[ii][r4b + 3] = kval(i0f + ii, r4b + 3);
  }
  __syncthreads();
  float acc2[4][4];
#pragma unroll
  for (int a = 0; a < 4; a++)
#pragma unroll
    for (int c = 0; c < 4; c++) acc2[a][c] = 0.0f;
#pragma unroll 8
  for (int ip = 0; ip < 64; ip++) {
    float4 kc = *(const float4*)&sH[ip][iq4];   // r-quad
    float4 mm = *(const float4*)&sK[ip][gq4];
    float kk2[4] = {kc.x, kc.y, kc.z, kc.w};
    float mv[4]  = {mm.x, mm.y, mm.z, mm.w};
#pragma unroll
    for (int dr = 0; dr < 4; dr++)
#pragma unroll
      for (int dg = 0; dg < 4; dg++)
        acc2[dr][dg] = fmaf(kk2[dr], mv[dg], acc2[dr][dg]);
  }

  // ---- slice sum (fixed order) + P write ----
  int slice = it * 4 + jq;
  float ps = 0.0f;
#pragma unroll
  for (int dr = 0; dr < 4; dr++)
#pragma unroll
    for (int dg = 0; dg < 4; dg++) ps += acc2[dr][dg];
  sred[tid] = ps;
  __syncthreads();
  for (int st = 128; st > 0; st >>= 1) {
    if (tid < st) sred[tid] += sred[tid + st];
    __syncthreads();
  }
  if (tid == 0) psumC[b * 16 + slice] = sred[0];

  float* Pb = Pp + ((size_t)b * 16 + slice) * 4096;
#pragma unroll
  for (int dr = 0; dr < 4; dr++) {
    float4 v = make_float4(acc2[dr][0], acc2[dr][1], acc2[dr][2], acc2[dr][3]);
    *(float4*)&Pb[(size_t)(iq4 + dr) * 64 + gq4] = v;
  }
}

// ---------------- K3: finalize — reduce 16 slices, normalize, store ----------------
// 64 blocks: b = bid&15 (keeps b%8 == bid%8 XCD match), sl4 = bid>>4 (quarter of rg space)
__global__ __launch_bounds__(256) void finalize(const float* __restrict__ Pp,
                                                const float* __restrict__ psumC,
                                                float* __restrict__ out) {
  const int bid = blockIdx.x;
  const int b = bid & 15;
  const int sl4 = bid >> 4;          // 0..3
  const int tid = threadIdx.x;
  const float* pc = psumC + b * 16;
  float tot = 0.0f;
#pragma unroll
  for (int c = 0; c < 16; c++) tot += pc[c];   // fixed order: deterministic
  float inv = 1.0f / (tot + EPS);
  int rg4 = sl4 * 1024 + tid * 4;
  const float* Pb = Pp + (size_t)b * 16 * 4096;
  float4 s = make_float4(0.f, 0.f, 0.f, 0.f);
#pragma unroll
  for (int c = 0; c < 16; c++) {
    float4 v = *(const float4*)&Pb[(size_t)c * 4096 + rg4];
    s.x += v.x; s.y += v.y; s.z += v.z; s.w += v.w;
  }
  s.x *= inv; s.y *= inv; s.z *= inv; s.w *= inv;
  *(float4*)&out[(size_t)b * 4096 + rg4] = s;
}

extern "C" void kernel_launch(void* const* d_in, const int* in_sizes, int n_in,
                              void* d_out, int out_size, void* d_ws, size_t ws_size,
                              hipStream_t stream) {
  const float* x = (const float*)d_in[0];
  float* out = (float*)d_out;

  char* p = (char*)d_ws;
  float* Hq = (float*)p;     p += (size_t)BATCH * 4 * 4 * 16384 * 4;  // 16 MB
  float* Pp = (float*)p;     p += (size_t)BATCH * 16 * 4096 * 4;      // 4 MB
  float* psumC = (float*)p;

  hist_direct<<<256, 1024, 0, stream>>>(x, Hq);
  stageBC<<<256, 256, 0, stream>>>(Hq, Pp, psumC);
  finalize<<<64, 256, 0, stream>>>(Pp, psumC, out);
}

// Round 10
// 29.418 us; speedup vs baseline: 6.3266x; 1.1968x over previous
//
#include <hip/hip_runtime.h>
#include <stdint.h>

#define BATCH 16
#define NPIX 200704      // 448*448
#define EPS 1e-6f
#define FW 256           // fine grid; i+j <= 255 structurally (chroma simplex)
#define NCHUNK 16        // pixel chunks per batch in K1
#define CHPX (NPIX / NCHUNK)     // 12544 pixels
#define CHF4 (CHPX / 4)          // 3136 float4 per plane
// packed-u16 trapezoid layout per (b,chunk): window w has 64 rows x WW(w)=128-32w words
#define SLABW 20480              // words per (b,chunk) slab: 64*(128+96+64+32)
#define SLABW4 5120              // uint4 per slab

// K(c,g) = 1 / (1 + ((cc - b_g)/sigma)^2), cc=(c+0.5)/FW, b_g=g/63, 1/sigma=50
__device__ __forceinline__ float kval(int c, int g) {
  float d = (((float)c + 0.5f) * (1.0f / (float)FW) - (float)g * (1.0f / 63.0f)) * 50.0f;
  return 1.0f / (1.0f + d * d);
}

// ---------------- K1: full-grid u16 histogram per (batch, pixel-chunk), x read once ----------------
__global__ __launch_bounds__(1024) void hist_full(const float* __restrict__ x,
                                                  unsigned int* __restrict__ Hq) {
  extern __shared__ unsigned int sh[];      // 32768 words = 65536 u16 bins (full 256x256)
  const int bid = blockIdx.x;
  const int tid = threadIdx.x;
  const int xcd = bid & 7;                  // batch pinned to XCD b%8
  const int t0 = bid >> 3;                  // 0..31
  const int chunk = t0 & (NCHUNK - 1);
  const int b = xcd + 8 * (t0 >> 4);

  {
    uint4* s4 = (uint4*)sh;
    uint4 z = make_uint4(0u, 0u, 0u, 0u);
    for (int t = tid; t < 8192; t += 1024) s4[t] = z;
  }
  __syncthreads();

  const float* xb = x + (size_t)b * 3 * NPIX;
  const float4* R  = (const float4*)xb + (size_t)chunk * CHF4;
  const float4* G  = (const float4*)(xb + NPIX) + (size_t)chunk * CHF4;
  const float4* Bl = (const float4*)(xb + 2 * NPIX) + (size_t)chunk * CHF4;

  for (int t = tid; t < CHF4; t += 1024) {
    float4 rv = R[t], gv = G[t], bv = Bl[t];
    float rr[4] = {rv.x, rv.y, rv.z, rv.w};
    float gg[4] = {gv.x, gv.y, gv.z, gv.w};
    float bb[4] = {bv.x, bv.y, bv.z, bv.w};
#pragma unroll
    for (int c = 0; c < 4; c++) {
      float r  = fminf(fmaxf(rr[c], 0.0f), 1.0f);
      float g  = fminf(fmaxf(gg[c], 0.0f), 1.0f);
      float bl = fminf(fmaxf(bb[c], 0.0f), 1.0f);
      float inv = 1.0f / (r + g + bl + EPS);
      int i = min((int)(r * inv * (float)FW), FW - 1);
      int j = min((int)(g * inv * (float)FW), FW - 1);
      unsigned int id = (unsigned int)((i << 8) | j);
      // packed u16: word = id>>1, half = id&1. Per-block adds = 12544 < 65536: no overflow.
      atomicAdd(&sh[id >> 1], 1u << ((id & 1u) << 4));
    }
  }
  __syncthreads();

  // flush trapezoid: window w -> 64 rows x (32-8w) uint4
  const uint4* sh4 = (const uint4*)sh;
  uint4* dst = (uint4*)Hq + (size_t)(b * NCHUNK + chunk) * SLABW4;
  const int woff4[4] = {0, 2048, 3584, 4608};
  const int wwu4[4]  = {32, 24, 16, 8};
#pragma unroll
  for (int w = 0; w < 4; w++) {
    int n = 64 * wwu4[w];
    for (int t = tid; t < n; t += 1024) {
      int rr = t / wwu4[w];                 // const-div after unroll
      int cu4 = t - rr * wwu4[w];
      dst[woff4[w] + t] = sh4[(size_t)(w * 64 + rr) * 32 + cu4];
    }
  }
}

// ---------------- K2: fused M-GEMM + K^T epilogue over the 10 nonzero tiles ----------------
// tile (it,jq), it+jq<=3: M[i][g] = sum_{j in jq-chunk} H[it*64+i][j]*K[j][g]
// P[b][sl][r][g] = sum_i K(it*64+i, r) * M[i][g];  psumC[b][sl] = slice total.
__constant__ int c_itA[10] = {0,0,0,0,1,1,1,2,2,3};
__constant__ int c_jqA[10] = {0,1,2,3,0,1,2,0,1,0};

__global__ __launch_bounds__(256) void stageBC(const unsigned int* __restrict__ Hq,
                                               float* __restrict__ Pp,
                                               float* __restrict__ psumC) {
  __shared__ float sH[64][68];   // H tile (padded); K_C in epilogue
  __shared__ float sK[64][64];   // K tile; M tile in epilogue
  __shared__ float sred[256];
  const int bid = blockIdx.x;    // 160 = xcd(8) x (10 tiles x 2 batch-halves)
  const int tid = threadIdx.x;
  const int xcd = bid & 7;
  const int t0 = bid >> 3;       // 0..19
  const int sl = (t0 < 10) ? t0 : t0 - 10;
  const int b = xcd + 8 * (t0 < 10 ? 0 : 1);
  const int it = c_itA[sl];
  const int jq = c_jqA[sl];
  const int gq4 = (tid & 15) * 4;
  const int iq4 = (tid >> 4) * 4;

  // ---- stage H tile: sum 16 chunk-partials (packed u16) ----
  {
    const int wslab4[4] = {0, 2048, 3584, 4608};
    const int ww4[4]    = {32, 24, 16, 8};
    const uint4* Hb = (const uint4*)Hq + (size_t)b * NCHUNK * SLABW4;
#pragma unroll
    for (int rep = 0; rep < 2; rep++) {
      int idx = rep * 256 + tid;           // 512 = 64 rows x 8 uint4-cols
      int row = idx >> 3, c8 = idx & 7;
      int base4 = wslab4[it] + row * ww4[it] + jq * 8 + c8;
      unsigned int acc[8] = {0,0,0,0,0,0,0,0};
      for (int ch = 0; ch < NCHUNK; ch++) {
        uint4 v = Hb[(size_t)ch * SLABW4 + base4];
        acc[0] += v.x & 0xFFFFu; acc[1] += v.x >> 16;
        acc[2] += v.y & 0xFFFFu; acc[3] += v.y >> 16;
        acc[4] += v.z & 0xFFFFu; acc[5] += v.z >> 16;
        acc[6] += v.w & 0xFFFFu; acc[7] += v.w >> 16;
      }
      int cc = c8 * 8;
      *(float4*)&sH[row][cc]     = make_float4((float)acc[0], (float)acc[1], (float)acc[2], (float)acc[3]);
      *(float4*)&sH[row][cc + 4] = make_float4((float)acc[4], (float)acc[5], (float)acc[6], (float)acc[7]);
    }
  }
  // ---- K tile for j-chunk ----
  int j0 = jq * 64;
#pragma unroll
  for (int rep = 0; rep < 4; rep++) {
    int idx = rep * 256 + tid;
    int jr = idx >> 4, g4 = (idx & 15) * 4;
    sK[jr][g4 + 0] = kval(j0 + jr, g4 + 0);
    sK[jr][g4 + 1] = kval(j0 + jr, g4 + 1);
    sK[jr][g4 + 2] = kval(j0 + jr, g4 + 2);
    sK[jr][g4 + 3] = kval(j0 + jr, g4 + 3);
  }
  __syncthreads();

  // ---- M-phase: acc[4][4] over 64 j ----
  float acc[4][4];
#pragma unroll
  for (int a = 0; a < 4; a++)
#pragma unroll
    for (int c = 0; c < 4; c++) acc[a][c] = 0.0f;
#pragma unroll 4
  for (int tt = 0; tt < 16; tt++) {
    float hh[4][4], kk[4][4];
#pragma unroll
    for (int di = 0; di < 4; di++) {
      float4 v = *(const float4*)&sH[iq4 + di][tt * 4];
      hh[di][0] = v.x; hh[di][1] = v.y; hh[di][2] = v.z; hh[di][3] = v.w;
    }
#pragma unroll
    for (int p = 0; p < 4; p++) {
      float4 v = *(const float4*)&sK[tt * 4 + p][gq4];
      kk[p][0] = v.x; kk[p][1] = v.y; kk[p][2] = v.z; kk[p][3] = v.w;
    }
#pragma unroll
    for (int p = 0; p < 4; p++)
#pragma unroll
      for (int di = 0; di < 4; di++)
#pragma unroll
        for (int dg = 0; dg < 4; dg++)
          acc[di][dg] = fmaf(hh[di][p], kk[p][dg], acc[di][dg]);
  }
  __syncthreads();

  // ---- epilogue: P_slice = K_C^T * M (on-chip) ----
#pragma unroll
  for (int di = 0; di < 4; di++) {
    float4 v = make_float4(acc[di][0], acc[di][1], acc[di][2], acc[di][3]);
    *(float4*)&sK[iq4 + di][gq4] = v;           // M tile: rows=i, cols=g
  }
  int i0f = it * 64;
#pragma unroll
  for (int rep = 0; rep < 4; rep++) {           // K_C: rows=i, cols=r
    int idx = rep * 256 + tid;
    int ii = idx >> 4, r4b = (idx & 15) * 4;
    sH[ii][r4b + 0] = kval(i0f + ii, r4b + 0);
    sH[ii][r4b + 1] = kval(i0f + ii, r4b + 1);
    sH[ii][r4b + 2] = kval(i0f + ii, r4b + 2);
    sH[ii][r4b + 3] = kval(i0f + ii, r4b + 3);
  }
  __syncthreads();
  float acc2[4][4];
#pragma unroll
  for (int a = 0; a < 4; a++)
#pragma unroll
    for (int c = 0; c < 4; c++) acc2[a][c] = 0.0f;
#pragma unroll 8
  for (int ip = 0; ip < 64; ip++) {
    float4 kc = *(const float4*)&sH[ip][iq4];   // r-quad
    float4 mm = *(const float4*)&sK[ip][gq4];
    float kk2[4] = {kc.x, kc.y, kc.z, kc.w};
    float mv[4]  = {mm.x, mm.y, mm.z, mm.w};
#pragma unroll
    for (int dr = 0; dr < 4; dr++)
#pragma unroll
      for (int dg = 0; dg < 4; dg++)
        acc2[dr][dg] = fmaf(kk2[dr], mv[dg], acc2[dr][dg]);
  }

  // ---- slice sum (fixed order) + P write ----
  float ps = 0.0f;
#pragma unroll
  for (int dr = 0; dr < 4; dr++)
#pragma unroll
    for (int dg = 0; dg < 4; dg++) ps += acc2[dr][dg];
  sred[tid] = ps;
  __syncthreads();
  for (int st = 128; st > 0; st >>= 1) {
    if (tid < st) sred[tid] += sred[tid + st];
    __syncthreads();
  }
  if (tid == 0) psumC[b * 10 + sl] = sred[0];

  float* Pb = Pp + ((size_t)b * 10 + sl) * 4096;
#pragma unroll
  for (int dr = 0; dr < 4; dr++) {
    float4 v = make_float4(acc2[dr][0], acc2[dr][1], acc2[dr][2], acc2[dr][3]);
    *(float4*)&Pb[(size_t)(iq4 + dr) * 64 + gq4] = v;
  }
}

// ---------------- K3: finalize — reduce 10 slices, normalize, store ----------------
__global__ __launch_bounds__(256) void finalize(const float* __restrict__ Pp,
                                                const float* __restrict__ psumC,
                                                float* __restrict__ out) {
  const int bid = blockIdx.x;        // 64 = b(16) x sl4(4); b&7 == bid&7 (XCD match)
  const int b = bid & 15;
  const int sl4 = bid >> 4;
  const int tid = threadIdx.x;
  const float* pc = psumC + b * 10;
  float tot = 0.0f;
#pragma unroll
  for (int c = 0; c < 10; c++) tot += pc[c];   // fixed order: deterministic
  float inv = 1.0f / (tot + EPS);
  int rg4 = sl4 * 1024 + tid * 4;
  const float* Pb = Pp + (size_t)b * 10 * 4096;
  float4 s = make_float4(0.f, 0.f, 0.f, 0.f);
#pragma unroll
  for (int c = 0; c < 10; c++) {
    float4 v = *(const float4*)&Pb[(size_t)c * 4096 + rg4];
    s.x += v.x; s.y += v.y; s.z += v.z; s.w += v.w;
  }
  s.x *= inv; s.y *= inv; s.z *= inv; s.w *= inv;
  *(float4*)&out[(size_t)b * 4096 + rg4] = s;
}

extern "C" void kernel_launch(void* const* d_in, const int* in_sizes, int n_in,
                              void* d_out, int out_size, void* d_ws, size_t ws_size,
                              hipStream_t stream) {
  const float* x = (const float*)d_in[0];
  float* out = (float*)d_out;

  char* p = (char*)d_ws;
  unsigned int* Hq = (unsigned int*)p;  p += (size_t)BATCH * NCHUNK * SLABW * 4;  // 20 MB
  float* Pp = (float*)p;                p += (size_t)BATCH * 10 * 4096 * 4;       // 2.6 MB
  float* psumC = (float*)p;

  hipFuncSetAttribute((const void*)hist_full,
                      hipFuncAttributeMaxDynamicSharedMemorySize, 131072);
  hist_full<<<256, 1024, 131072, stream>>>(x, Hq);
  stageBC<<<160, 256, 0, stream>>>(Hq, Pp, psumC);
  finalize<<<64, 256, 0, stream>>>(Pp, psumC, out);
}

// Round 11
// 26.904 us; speedup vs baseline: 6.9176x; 1.0934x over previous
//
#include <hip/hip_runtime.h>
#include <stdint.h>

#define BATCH 16
#define NPIX 200704      // 448*448
#define EPS 1e-6f
#define FW 192           // fine grid; i+j <= 191 structurally (chroma simplex)
#define NCHUNK 16        // pixel chunks per batch in K1
#define CHPX (NPIX / NCHUNK)     // 12544 pixels  (u16-safe: < 65536)
#define CHF4 (CHPX / 4)          // 3136 float4 per plane
#define NTILE 6          // nonzero 64x64 tiles: it+jq <= 2
#define SLAB4 (NTILE * 512)      // uint4 per (b,chunk) slab: 6 tiles x 64 rows x 8 uint4

// tile list (same order used by flush, stageBC, finalize)
__constant__ int c_itA[NTILE] = {0, 0, 0, 1, 1, 2};
__constant__ int c_jqA[NTILE] = {0, 1, 2, 0, 1, 0};

// K(c,g) = 1 / (1 + ((cc - b_g)/sigma)^2), cc=(c+0.5)/FW, b_g=g/63, 1/sigma=50
__device__ __forceinline__ float kval(int c, int g) {
  float d = (((float)c + 0.5f) * (1.0f / (float)FW) - (float)g * (1.0f / 63.0f)) * 50.0f;
  return 1.0f / (1.0f + d * d);
}

// ---------------- K1: full-grid u16 histogram per (batch, pixel-chunk), x read once ----------------
// LDS = 192*192 u16 bins = 72 KB -> 2 blocks/CU (32 waves/CU).
__global__ __launch_bounds__(1024) void hist_full(const float* __restrict__ x,
                                                  unsigned int* __restrict__ Hq) {
  extern __shared__ unsigned int sh[];      // 18432 words = 36864 u16 bins
  const int bid = blockIdx.x;
  const int tid = threadIdx.x;
  const int xcd = bid & 7;                  // batch pinned to XCD b%8
  const int t0 = bid >> 3;                  // 0..31
  const int chunk = t0 & (NCHUNK - 1);
  const int b = xcd + 8 * (t0 >> 4);

  {
    uint4* s4 = (uint4*)sh;
    uint4 z = make_uint4(0u, 0u, 0u, 0u);
    for (int t = tid; t < 4608; t += 1024) s4[t] = z;
  }
  __syncthreads();

  const float* xb = x + (size_t)b * 3 * NPIX;
  const float4* R  = (const float4*)xb + (size_t)chunk * CHF4;
  const float4* G  = (const float4*)(xb + NPIX) + (size_t)chunk * CHF4;
  const float4* Bl = (const float4*)(xb + 2 * NPIX) + (size_t)chunk * CHF4;

  for (int t = tid; t < CHF4; t += 1024) {
    float4 rv = R[t], gv = G[t], bv = Bl[t];
    float rr[4] = {rv.x, rv.y, rv.z, rv.w};
    float gg[4] = {gv.x, gv.y, gv.z, gv.w};
    float bb[4] = {bv.x, bv.y, bv.z, bv.w};
#pragma unroll
    for (int c = 0; c < 4; c++) {
      float r  = fminf(fmaxf(rr[c], 0.0f), 1.0f);
      float g  = fminf(fmaxf(gg[c], 0.0f), 1.0f);
      float bl = fminf(fmaxf(bb[c], 0.0f), 1.0f);
      float inv = 1.0f / (r + g + bl + EPS);
      int i = min((int)(r * inv * (float)FW), FW - 1);
      int j = min((int)(g * inv * (float)FW), FW - 1);
      unsigned int id = (unsigned int)(i * FW + j);
      // packed u16: word = id>>1, half = id&1. Per-block adds = 12544 < 65536: no overflow.
      atomicAdd(&sh[id >> 1], 1u << ((id & 1u) << 4));
    }
  }
  __syncthreads();

  // flush the 6 nonzero 64x64 tiles (i+j<=191 => tiles with it+jq<=2 cover all nonzeros)
  const uint4* sh4 = (const uint4*)sh;
  uint4* dst = (uint4*)Hq + (size_t)(b * NCHUNK + chunk) * SLAB4;
  for (int t = tid; t < SLAB4; t += 1024) {        // 3072 = 3 iters
    int tno = t >> 9;                              // tile 0..5
    int rem = t & 511;
    int row = rem >> 3, c4 = rem & 7;
    int it = c_itA[tno], jq = c_jqA[tno];
    // u16 row start = (it*64+row)*192 + jq*64 -> uint4 index = /8
    dst[t] = sh4[(it * 64 + row) * 24 + jq * 8 + c4];
  }
}

// ---------------- K2: fused M-GEMM + K^T epilogue over the 6 nonzero tiles ----------------
// tile (it,jq): M[i][g] = sum_{j in jq-chunk} H[it*64+i][j]*K[j][g]
// P[b][sl][r][g] = sum_i K(it*64+i, r) * M[i][g];  psumC[b][sl] = slice total.
__global__ __launch_bounds__(256) void stageBC(const unsigned int* __restrict__ Hq,
                                               float* __restrict__ Pp,
                                               float* __restrict__ psumC) {
  __shared__ float sH[64][68];   // H tile (padded); K_C in epilogue
  __shared__ float sK[64][64];   // K tile; M tile in epilogue
  __shared__ float sred[256];
  const int bid = blockIdx.x;    // 96 = xcd(8) x (6 tiles x 2 batch-halves)
  const int tid = threadIdx.x;
  const int xcd = bid & 7;
  const int t0 = bid >> 3;       // 0..11
  const int sl = (t0 < NTILE) ? t0 : t0 - NTILE;
  const int b = xcd + 8 * (t0 < NTILE ? 0 : 1);
  const int it = c_itA[sl];
  const int jq = c_jqA[sl];
  const int gq4 = (tid & 15) * 4;
  const int iq4 = (tid >> 4) * 4;

  // ---- stage H tile: sum 16 chunk-partials (packed u16, tile-contiguous) ----
  {
    const uint4* Hb = (const uint4*)Hq + (size_t)b * NCHUNK * SLAB4;
#pragma unroll
    for (int rep = 0; rep < 2; rep++) {
      int idx = rep * 256 + tid;           // 512 = 64 rows x 8 uint4-cols
      int row = idx >> 3, c8 = idx & 7;
      int base4 = sl * 512 + row * 8 + c8;
      unsigned int acc[8] = {0,0,0,0,0,0,0,0};
      for (int ch = 0; ch < NCHUNK; ch++) {
        uint4 v = Hb[(size_t)ch * SLAB4 + base4];
        acc[0] += v.x & 0xFFFFu; acc[1] += v.x >> 16;
        acc[2] += v.y & 0xFFFFu; acc[3] += v.y >> 16;
        acc[4] += v.z & 0xFFFFu; acc[5] += v.z >> 16;
        acc[6] += v.w & 0xFFFFu; acc[7] += v.w >> 16;
      }
      int cc = c8 * 8;
      *(float4*)&sH[row][cc]     = make_float4((float)acc[0], (float)acc[1], (float)acc[2], (float)acc[3]);
      *(float4*)&sH[row][cc + 4] = make_float4((float)acc[4], (float)acc[5], (float)acc[6], (float)acc[7]);
    }
  }
  // ---- K tile for j-chunk ----
  int j0 = jq * 64;
#pragma unroll
  for (int rep = 0; rep < 4; rep++) {
    int idx = rep * 256 + tid;
    int jr = idx >> 4, g4 = (idx & 15) * 4;
    sK[jr][g4 + 0] = kval(j0 + jr, g4 + 0);
    sK[jr][g4 + 1] = kval(j0 + jr, g4 + 1);
    sK[jr][g4 + 2] = kval(j0 + jr, g4 + 2);
    sK[jr][g4 + 3] = kval(j0 + jr, g4 + 3);
  }
  __syncthreads();

  // ---- M-phase: acc[4][4] over 64 j ----
  float acc[4][4];
#pragma unroll
  for (int a = 0; a < 4; a++)
#pragma unroll
    for (int c = 0; c < 4; c++) acc[a][c] = 0.0f;
#pragma unroll 4
  for (int tt = 0; tt < 16; tt++) {
    float hh[4][4], kk[4][4];
#pragma unroll
    for (int di = 0; di < 4; di++) {
      float4 v = *(const float4*)&sH[iq4 + di][tt * 4];
      hh[di][0] = v.x; hh[di][1] = v.y; hh[di][2] = v.z; hh[di][3] = v.w;
    }
#pragma unroll
    for (int p = 0; p < 4; p++) {
      float4 v = *(const float4*)&sK[tt * 4 + p][gq4];
      kk[p][0] = v.x; kk[p][1] = v.y; kk[p][2] = v.z; kk[p][3] = v.w;
    }
#pragma unroll
    for (int p = 0; p < 4; p++)
#pragma unroll
      for (int di = 0; di < 4; di++)
#pragma unroll
        for (int dg = 0; dg < 4; dg++)
          acc[di][dg] = fmaf(hh[di][p], kk[p][dg], acc[di][dg]);
  }
  __syncthreads();

  // ---- epilogue: P_slice = K_C^T * M (on-chip) ----
#pragma unroll
  for (int di = 0; di < 4; di++) {
    float4 v = make_float4(acc[di][0], acc[di][1], acc[di][2], acc[di][3]);
    *(float4*)&sK[iq4 + di][gq4] = v;           // M tile: rows=i, cols=g
  }
  int i0f = it * 64;
#pragma unroll
  for (int rep = 0; rep < 4; rep++) {           // K_C: rows=i, cols=r
    int idx = rep * 256 + tid;
    int ii = idx >> 4, r4b = (idx & 15) * 4;
    sH[ii][r4b + 0] = kval(i0f + ii, r4b + 0);
    sH[ii][r4b + 1] = kval(i0f + ii, r4b + 1);
    sH[ii][r4b + 2] = kval(i0f + ii, r4b + 2);
    sH[ii][r4b + 3] = kval(i0f + ii, r4b + 3);
  }
  __syncthreads();
  float acc2[4][4];
#pragma unroll
  for (int a = 0; a < 4; a++)
#pragma unroll
    for (int c = 0; c < 4; c++) acc2[a][c] = 0.0f;
#pragma unroll 8
  for (int ip = 0; ip < 64; ip++) {
    float4 kc = *(const float4*)&sH[ip][iq4];   // r-quad
    float4 mm = *(const float4*)&sK[ip][gq4];
    float kk2[4] = {kc.x, kc.y, kc.z, kc.w};
    float mv[4]  = {mm.x, mm.y, mm.z, mm.w};
#pragma unroll
    for (int dr = 0; dr < 4; dr++)
#pragma unroll
      for (int dg = 0; dg < 4; dg++)
        acc2[dr][dg] = fmaf(kk2[dr], mv[dg], acc2[dr][dg]);
  }

  // ---- slice sum (fixed order) + P write ----
  float ps = 0.0f;
#pragma unroll
  for (int dr = 0; dr < 4; dr++)
#pragma unroll
    for (int dg = 0; dg < 4; dg++) ps += acc2[dr][dg];
  sred[tid] = ps;
  __syncthreads();
  for (int st = 128; st > 0; st >>= 1) {
    if (tid < st) sred[tid] += sred[tid + st];
    __syncthreads();
  }
  if (tid == 0) psumC[b * NTILE + sl] = sred[0];

  float* Pb = Pp + ((size_t)b * NTILE + sl) * 4096;
#pragma unroll
  for (int dr = 0; dr < 4; dr++) {
    float4 v = make_float4(acc2[dr][0], acc2[dr][1], acc2[dr][2], acc2[dr][3]);
    *(float4*)&Pb[(size_t)(iq4 + dr) * 64 + gq4] = v;
  }
}

// ---------------- K3: finalize — reduce 6 slices, normalize, store ----------------
__global__ __launch_bounds__(256) void finalize(const float* __restrict__ Pp,
                                                const float* __restrict__ psumC,
                                                float* __restrict__ out) {
  const int bid = blockIdx.x;        // 64 = b(16) x sl4(4); b&7 == bid&7 (XCD match)
  const int b = bid & 15;
  const int sl4 = bid >> 4;
  const int tid = threadIdx.x;
  const float* pc = psumC + b * NTILE;
  float tot = 0.0f;
#pragma unroll
  for (int c = 0; c < NTILE; c++) tot += pc[c];  // fixed order: deterministic
  float inv = 1.0f / (tot + EPS);
  int rg4 = sl4 * 1024 + tid * 4;
  const float* Pb = Pp + (size_t)b * NTILE * 4096;
  float4 s = make_float4(0.f, 0.f, 0.f, 0.f);
#pragma unroll
  for (int c = 0; c < NTILE; c++) {
    float4 v = *(const float4*)&Pb[(size_t)c * 4096 + rg4];
    s.x += v.x; s.y += v.y; s.z += v.z; s.w += v.w;
  }
  s.x *= inv; s.y *= inv; s.z *= inv; s.w *= inv;
  *(float4*)&out[(size_t)b * 4096 + rg4] = s;
}

extern "C" void kernel_launch(void* const* d_in, const int* in_sizes, int n_in,
                              void* d_out, int out_size, void* d_ws, size_t ws_size,
                              hipStream_t stream) {
  const float* x = (const float*)d_in[0];
  float* out = (float*)d_out;

  char* p = (char*)d_ws;
  unsigned int* Hq = (unsigned int*)p;  p += (size_t)BATCH * NCHUNK * SLAB4 * 16;  // 12.6 MB
  float* Pp = (float*)p;                p += (size_t)BATCH * NTILE * 4096 * 4;     // 1.6 MB
  float* psumC = (float*)p;

  hipFuncSetAttribute((const void*)hist_full,
                      hipFuncAttributeMaxDynamicSharedMemorySize, 73728);
  hist_full<<<256, 1024, 73728, stream>>>(x, Hq);
  stageBC<<<96, 256, 0, stream>>>(Hq, Pp, psumC);
  finalize<<<64, 256, 0, stream>>>(Pp, psumC, out);
}

// Round 12
// 24.817 us; speedup vs baseline: 7.4994x; 1.0841x over previous
//
#include <hip/hip_runtime.h>
#include <stdint.h>

#define BATCH 16
#define NPIX 200704      // 448*448
#define EPS 1e-6f
#define FW 192           // fine grid; i+j <= 191 structurally (chroma simplex)
#define NCHUNK 16        // pixel chunks per batch in K1
#define CHPX (NPIX / NCHUNK)     // 12544 pixels  (u16-safe: < 65536)
#define CHF4 (CHPX / 4)          // 3136 float4 per plane
#define NTILE 6          // nonzero 64x64 tiles: it+jq <= 2
#define NSLICE 12        // 6 tiles x 2 i-halves
#define SLAB4 (NTILE * 512)      // uint4 per (b,chunk) slab: 6 tiles x 64 rows x 8 uint4

// tile list (same order used by flush, stageBC)
__constant__ int c_itA[NTILE] = {0, 0, 0, 1, 1, 2};
__constant__ int c_jqA[NTILE] = {0, 1, 2, 0, 1, 0};

// K(c,g) = 1 / (1 + ((cc - b_g)/sigma)^2), cc=(c+0.5)/FW, b_g=g/63, 1/sigma=50
__device__ __forceinline__ float kval(int c, int g) {
  float d = (((float)c + 0.5f) * (1.0f / (float)FW) - (float)g * (1.0f / 63.0f)) * 50.0f;
  return 1.0f / (1.0f + d * d);
}

// ---------------- K1: full-grid u16 histogram per (batch, pixel-chunk), x read once ----------------
// LDS = 192*192 u16 bins = 72 KB -> 2 blocks/CU (32 waves/CU).
__global__ __launch_bounds__(1024) void hist_full(const float* __restrict__ x,
                                                  unsigned int* __restrict__ Hq) {
  extern __shared__ unsigned int sh[];      // 18432 words = 36864 u16 bins
  const int bid = blockIdx.x;
  const int tid = threadIdx.x;
  const int xcd = bid & 7;                  // batch pinned to XCD b%8
  const int t0 = bid >> 3;                  // 0..31
  const int chunk = t0 & (NCHUNK - 1);
  const int b = xcd + 8 * (t0 >> 4);

  {
    uint4* s4 = (uint4*)sh;
    uint4 z = make_uint4(0u, 0u, 0u, 0u);
    for (int t = tid; t < 4608; t += 1024) s4[t] = z;
  }
  __syncthreads();

  const float* xb = x + (size_t)b * 3 * NPIX;
  const float4* R  = (const float4*)xb + (size_t)chunk * CHF4;
  const float4* G  = (const float4*)(xb + NPIX) + (size_t)chunk * CHF4;
  const float4* Bl = (const float4*)(xb + 2 * NPIX) + (size_t)chunk * CHF4;

  for (int t = tid; t < CHF4; t += 1024) {
    float4 rv = R[t], gv = G[t], bv = Bl[t];
    float rr[4] = {rv.x, rv.y, rv.z, rv.w};
    float gg[4] = {gv.x, gv.y, gv.z, gv.w};
    float bb[4] = {bv.x, bv.y, bv.z, bv.w};
#pragma unroll
    for (int c = 0; c < 4; c++) {
      float r  = fminf(fmaxf(rr[c], 0.0f), 1.0f);
      float g  = fminf(fmaxf(gg[c], 0.0f), 1.0f);
      float bl = fminf(fmaxf(bb[c], 0.0f), 1.0f);
      float inv = 1.0f / (r + g + bl + EPS);
      int i = min((int)(r * inv * (float)FW), FW - 1);
      int j = min((int)(g * inv * (float)FW), FW - 1);
      unsigned int id = (unsigned int)(i * FW + j);
      // packed u16: word = id>>1, half = id&1. Per-block adds = 12544 < 65536: no overflow.
      atomicAdd(&sh[id >> 1], 1u << ((id & 1u) << 4));
    }
  }
  __syncthreads();

  // flush the 6 nonzero 64x64 tiles (i+j<=191 => tiles with it+jq<=2 cover all nonzeros)
  const uint4* sh4 = (const uint4*)sh;
  uint4* dst = (uint4*)Hq + (size_t)(b * NCHUNK + chunk) * SLAB4;
  for (int t = tid; t < SLAB4; t += 1024) {        // 3072 = 3 iters
    int tno = t >> 9;                              // tile 0..5
    int rem = t & 511;
    int row = rem >> 3, c4 = rem & 7;
    int it = c_itA[tno], jq = c_jqA[tno];
    // u16 row start = (it*64+row)*192 + jq*64 -> uint4 index = /8 (192 u16 = 24 uint4/row)
    dst[t] = sh4[(it * 64 + row) * 24 + jq * 8 + c4];
  }
}

// ---------------- K2: fused M-GEMM + K^T epilogue, split over i-halves ----------------
// block (b, tile sl, i-half ih): rows i in [it*64+ih*32, +32)
//   M[i][g] = sum_{j in jq-chunk} H[i][j]*K(j,g)          (32x64, registers->LDS)
//   P[b][sl*2+ih][r][g] = sum_{ip<32} K(i0+ip, r)*M[ip][g];  psumC = slice total.
__global__ __launch_bounds__(256) void stageBC(const unsigned int* __restrict__ Hq,
                                               float* __restrict__ Pp,
                                               float* __restrict__ psumC) {
  __shared__ float sH[32][68];   // H half-tile (padded); M tile in epilogue
  __shared__ float sK[64][64];   // K tile; K_C (rows 0..31) in epilogue
  __shared__ float sred[256];
  const int bid = blockIdx.x;    // 192 = xcd(8) x 24;  24 = ih(2) x sl(6) x bh(2)
  const int tid = threadIdx.x;
  const int xcd = bid & 7;
  const int t0 = bid >> 3;       // 0..23
  const int ih = t0 & 1;
  const int rest = t0 >> 1;      // 0..11
  const int sl = (rest < NTILE) ? rest : rest - NTILE;
  const int b = xcd + 8 * (rest < NTILE ? 0 : 1);
  const int it = c_itA[sl];
  const int jq = c_jqA[sl];
  const int gq4 = (tid & 15) * 4;
  const int iq2 = (tid >> 4) * 2;        // 2 i-rows per thread in M-phase

  // ---- stage H half-tile: sum 16 chunk-partials (packed u16, tile-contiguous) ----
  {
    const uint4* Hb = (const uint4*)Hq + (size_t)b * NCHUNK * SLAB4;
    int row = tid >> 3, c8 = tid & 7;            // 256 threads = 32 rows x 8 uint4
    int base4 = sl * 512 + (ih * 32 + row) * 8 + c8;
    unsigned int acc[8] = {0,0,0,0,0,0,0,0};
#pragma unroll
    for (int ch = 0; ch < NCHUNK; ch++) {
      uint4 v = Hb[(size_t)ch * SLAB4 + base4];
      acc[0] += v.x & 0xFFFFu; acc[1] += v.x >> 16;
      acc[2] += v.y & 0xFFFFu; acc[3] += v.y >> 16;
      acc[4] += v.z & 0xFFFFu; acc[5] += v.z >> 16;
      acc[6] += v.w & 0xFFFFu; acc[7] += v.w >> 16;
    }
    int cc = c8 * 8;
    *(float4*)&sH[row][cc]     = make_float4((float)acc[0], (float)acc[1], (float)acc[2], (float)acc[3]);
    *(float4*)&sH[row][cc + 4] = make_float4((float)acc[4], (float)acc[5], (float)acc[6], (float)acc[7]);
  }
  // ---- K tile for j-chunk ----
  int j0 = jq * 64;
#pragma unroll
  for (int rep = 0; rep < 4; rep++) {
    int idx = rep * 256 + tid;
    int jr = idx >> 4, g4 = (idx & 15) * 4;
    sK[jr][g4 + 0] = kval(j0 + jr, g4 + 0);
    sK[jr][g4 + 1] = kval(j0 + jr, g4 + 1);
    sK[jr][g4 + 2] = kval(j0 + jr, g4 + 2);
    sK[jr][g4 + 3] = kval(j0 + jr, g4 + 3);
  }
  __syncthreads();

  // ---- M-phase: acc[2][4] over 64 j ----
  float acc[2][4];
#pragma unroll
  for (int a = 0; a < 2; a++)
#pragma unroll
    for (int c = 0; c < 4; c++) acc[a][c] = 0.0f;
#pragma unroll 4
  for (int tt = 0; tt < 16; tt++) {
    float hh[2][4], kk[4][4];
#pragma unroll
    for (int di = 0; di < 2; di++) {
      float4 v = *(const float4*)&sH[iq2 + di][tt * 4];
      hh[di][0] = v.x; hh[di][1] = v.y; hh[di][2] = v.z; hh[di][3] = v.w;
    }
#pragma unroll
    for (int p = 0; p < 4; p++) {
      float4 v = *(const float4*)&sK[tt * 4 + p][gq4];
      kk[p][0] = v.x; kk[p][1] = v.y; kk[p][2] = v.z; kk[p][3] = v.w;
    }
#pragma unroll
    for (int p = 0; p < 4; p++)
#pragma unroll
      for (int di = 0; di < 2; di++)
#pragma unroll
        for (int dg = 0; dg < 4; dg++)
          acc[di][dg] = fmaf(hh[di][p], kk[p][dg], acc[di][dg]);
  }
  __syncthreads();

  // ---- epilogue: P_half = K_C^T * M_half (on-chip) ----
#pragma unroll
  for (int di = 0; di < 2; di++) {
    float4 v = make_float4(acc[di][0], acc[di][1], acc[di][2], acc[di][3]);
    *(float4*)&sH[iq2 + di][gq4] = v;           // M half-tile: rows=ip, cols=g
  }
  int i0f = it * 64 + ih * 32;
#pragma unroll
  for (int rep = 0; rep < 2; rep++) {           // K_C: rows=ip (0..31), cols=r
    int idx = rep * 256 + tid;
    int ii = idx >> 4, r4b = (idx & 15) * 4;
    sK[ii][r4b + 0] = kval(i0f + ii, r4b + 0);
    sK[ii][r4b + 1] = kval(i0f + ii, r4b + 1);
    sK[ii][r4b + 2] = kval(i0f + ii, r4b + 2);
    sK[ii][r4b + 3] = kval(i0f + ii, r4b + 3);
  }
  __syncthreads();
  const int r4q = (tid >> 4) * 4;
  float acc2[4][4];
#pragma unroll
  for (int a = 0; a < 4; a++)
#pragma unroll
    for (int c = 0; c < 4; c++) acc2[a][c] = 0.0f;
#pragma unroll 8
  for (int ip = 0; ip < 32; ip++) {
    float4 kc = *(const float4*)&sK[ip][r4q];   // r-quad (broadcast in 16-lane groups)
    float4 mm = *(const float4*)&sH[ip][gq4];
    float kk2[4] = {kc.x, kc.y, kc.z, kc.w};
    float mv[4]  = {mm.x, mm.y, mm.z, mm.w};
#pragma unroll
    for (int dr = 0; dr < 4; dr++)
#pragma unroll
      for (int dg = 0; dg < 4; dg++)
        acc2[dr][dg] = fmaf(kk2[dr], mv[dg], acc2[dr][dg]);
  }

  // ---- slice sum (fixed order) + P write ----
  int sl2 = sl * 2 + ih;
  float ps = 0.0f;
#pragma unroll
  for (int dr = 0; dr < 4; dr++)
#pragma unroll
    for (int dg = 0; dg < 4; dg++) ps += acc2[dr][dg];
  sred[tid] = ps;
  __syncthreads();
  for (int st = 128; st > 0; st >>= 1) {
    if (tid < st) sred[tid] += sred[tid + st];
    __syncthreads();
  }
  if (tid == 0) psumC[b * NSLICE + sl2] = sred[0];

  float* Pb = Pp + ((size_t)b * NSLICE + sl2) * 4096;
#pragma unroll
  for (int dr = 0; dr < 4; dr++) {
    float4 v = make_float4(acc2[dr][0], acc2[dr][1], acc2[dr][2], acc2[dr][3]);
    *(float4*)&Pb[(size_t)(r4q + dr) * 64 + gq4] = v;
  }
}

// ---------------- K3: finalize — reduce 12 slices, normalize, store ----------------
__global__ __launch_bounds__(256) void finalize(const float* __restrict__ Pp,
                                                const float* __restrict__ psumC,
                                                float* __restrict__ out) {
  const int bid = blockIdx.x;        // 64 = b(16) x sl4(4); b&7 == bid&7 (XCD match)
  const int b = bid & 15;
  const int sl4 = bid >> 4;
  const int tid = threadIdx.x;
  const float* pc = psumC + b * NSLICE;
  float tot = 0.0f;
#pragma unroll
  for (int c = 0; c < NSLICE; c++) tot += pc[c];  // fixed order: deterministic
  float inv = 1.0f / (tot + EPS);
  int rg4 = sl4 * 1024 + tid * 4;
  const float* Pb = Pp + (size_t)b * NSLICE * 4096;
  float4 s = make_float4(0.f, 0.f, 0.f, 0.f);
#pragma unroll
  for (int c = 0; c < NSLICE; c++) {
    float4 v = *(const float4*)&Pb[(size_t)c * 4096 + rg4];
    s.x += v.x; s.y += v.y; s.z += v.z; s.w += v.w;
  }
  s.x *= inv; s.y *= inv; s.z *= inv; s.w *= inv;
  *(float4*)&out[(size_t)b * 4096 + rg4] = s;
}

extern "C" void kernel_launch(void* const* d_in, const int* in_sizes, int n_in,
                              void* d_out, int out_size, void* d_ws, size_t ws_size,
                              hipStream_t stream) {
  const float* x = (const float*)d_in[0];
  float* out = (float*)d_out;

  char* p = (char*)d_ws;
  unsigned int* Hq = (unsigned int*)p;  p += (size_t)BATCH * NCHUNK * SLAB4 * 16;  // 12.6 MB
  float* Pp = (float*)p;                p += (size_t)BATCH * NSLICE * 4096 * 4;    // 3.1 MB
  float* psumC = (float*)p;

  hipFuncSetAttribute((const void*)hist_full,
                      hipFuncAttributeMaxDynamicSharedMemorySize, 73728);
  hist_full<<<256, 1024, 73728, stream>>>(x, Hq);
  stageBC<<<192, 256, 0, stream>>>(Hq, Pp, psumC);
  finalize<<<64, 256, 0, stream>>>(Pp, psumC, out);
}

// Round 13
// 21.967 us; speedup vs baseline: 8.4723x; 1.1297x over previous
//
#include <hip/hip_runtime.h>
#include <stdint.h>

#define BATCH 16
#define NPIX 200704      // 448*448
#define EPS 1e-6f
#define FW 128           // fine grid; i+j <= 127 structurally (chroma simplex)
#define NCHUNK 16        // pixel chunks per batch in K1
#define CHPX (NPIX / NCHUNK)     // 12544 pixels  (u16-safe: < 65536)
#define CHF4 (CHPX / 4)          // 3136 float4 per plane
#define NTILE 3          // nonzero 64x64 tiles: it+jq <= 1
#define NSLICE 12        // 3 tiles x 4 i-quarters
#define SLAB4 (NTILE * 512)      // uint4 per (b,chunk) slab: 3 tiles x 64 rows x 8 uint4

// tile list (same order used by flush, stageBC)
__constant__ int c_itA[NTILE] = {0, 0, 1};
__constant__ int c_jqA[NTILE] = {0, 1, 0};

// K(c,g) = 1 / (1 + ((cc - b_g)/sigma)^2), cc=(c+0.5)/FW, b_g=g/63, 1/sigma=50
__device__ __forceinline__ float kval(int c, int g) {
  float d = (((float)c + 0.5f) * (1.0f / (float)FW) - (float)g * (1.0f / 63.0f)) * 50.0f;
  return 1.0f / (1.0f + d * d);
}

// ---------------- K1: full-grid u16 histogram per (batch, pixel-chunk), x read once ----------------
// LDS = 128*128 u16 bins = 32 KB static.
__global__ __launch_bounds__(1024) void hist_full(const float* __restrict__ x,
                                                  unsigned int* __restrict__ Hq) {
  __shared__ unsigned int sh[8192];         // 8192 words = 16384 u16 bins
  const int bid = blockIdx.x;
  const int tid = threadIdx.x;
  const int xcd = bid & 7;                  // batch pinned to XCD b%8
  const int t0 = bid >> 3;                  // 0..31
  const int chunk = t0 & (NCHUNK - 1);
  const int b = xcd + 8 * (t0 >> 4);

  {
    uint4* s4 = (uint4*)sh;
    uint4 z = make_uint4(0u, 0u, 0u, 0u);
    for (int t = tid; t < 2048; t += 1024) s4[t] = z;
  }
  __syncthreads();

  const float* xb = x + (size_t)b * 3 * NPIX;
  const float4* R  = (const float4*)xb + (size_t)chunk * CHF4;
  const float4* G  = (const float4*)(xb + NPIX) + (size_t)chunk * CHF4;
  const float4* Bl = (const float4*)(xb + 2 * NPIX) + (size_t)chunk * CHF4;

  for (int t = tid; t < CHF4; t += 1024) {
    float4 rv = R[t], gv = G[t], bv = Bl[t];
    float rr[4] = {rv.x, rv.y, rv.z, rv.w};
    float gg[4] = {gv.x, gv.y, gv.z, gv.w};
    float bb[4] = {bv.x, bv.y, bv.z, bv.w};
#pragma unroll
    for (int c = 0; c < 4; c++) {
      float r  = fminf(fmaxf(rr[c], 0.0f), 1.0f);
      float g  = fminf(fmaxf(gg[c], 0.0f), 1.0f);
      float bl = fminf(fmaxf(bb[c], 0.0f), 1.0f);
      float inv = 1.0f / (r + g + bl + EPS);
      int i = min((int)(r * inv * (float)FW), FW - 1);
      int j = min((int)(g * inv * (float)FW), FW - 1);
      unsigned int id = (unsigned int)((i << 7) | j);
      // packed u16: word = id>>1, half = id&1. Per-block adds = 12544 < 65536: no overflow.
      atomicAdd(&sh[id >> 1], 1u << ((id & 1u) << 4));
    }
  }
  __syncthreads();

  // flush the 3 nonzero 64x64 tiles (i+j<=127 => tiles with it+jq<=1 cover all nonzeros)
  const uint4* sh4 = (const uint4*)sh;
  uint4* dst = (uint4*)Hq + (size_t)(b * NCHUNK + chunk) * SLAB4;
  for (int t = tid; t < SLAB4; t += 1024) {        // 1536 -> 2 iters (2nd partial)
    int tno = t >> 9;                              // tile 0..2
    int rem = t & 511;
    int row = rem >> 3, c4 = rem & 7;
    int it = c_itA[tno], jq = c_jqA[tno];
    // u16 row = 128 bins = 16 uint4; col block jq*64 u16 = 8 uint4
    dst[t] = sh4[(it * 64 + row) * 16 + jq * 8 + c4];
  }
}

// ---------------- K2: fused M-GEMM + K^T epilogue, split over i-quarters ----------------
// block (b, tile sl, quarter qh): rows i in [it*64+qh*16, +16)
//   M[ip][g] = sum_{j in jq-chunk} H[i0+ip][j]*K(j,g)     (16x64, registers->LDS)
//   P[b][sl*4+qh][r][g] = sum_{ip<16} K(i0+ip, r)*M[ip][g];  psumC = slice total.
__global__ __launch_bounds__(256) void stageBC(const unsigned int* __restrict__ Hq,
                                               float* __restrict__ Pp,
                                               float* __restrict__ psumC) {
  __shared__ float sH[16][68];   // H quarter-tile (padded); M tile in epilogue
  __shared__ float sK[64][64];   // K tile; K_C (rows 0..15) in epilogue
  __shared__ float sred[256];
  const int bid = blockIdx.x;    // 192 = xcd(8) x 24;  24 = qh(4) x sl(3) x bh(2)
  const int tid = threadIdx.x;
  const int xcd = bid & 7;
  const int t0 = bid >> 3;       // 0..23
  const int qh = t0 & 3;
  const int rest = t0 >> 2;      // 0..5
  const int sl = (rest < NTILE) ? rest : rest - NTILE;
  const int b = xcd + 8 * (rest < NTILE ? 0 : 1);
  const int it = c_itA[sl];
  const int jq = c_jqA[sl];
  const int gq4 = (tid & 15) * 4;
  const int row_i = tid >> 4;            // one i-row per thread in M-phase (0..15)

  // ---- stage H quarter-tile: sum 16 chunk-partials (packed u16, tile-contiguous) ----
  if (tid < 128) {
    const uint4* Hb = (const uint4*)Hq + (size_t)b * NCHUNK * SLAB4;
    int row = tid >> 3, c8 = tid & 7;            // 128 lanes = 16 rows x 8 uint4
    int base4 = sl * 512 + (qh * 16 + row) * 8 + c8;
    unsigned int acc0[8] = {0,0,0,0,0,0,0,0};
#pragma unroll
    for (int ch = 0; ch < NCHUNK; ch++) {
      uint4 v = Hb[(size_t)ch * SLAB4 + base4];
      acc0[0] += v.x & 0xFFFFu; acc0[1] += v.x >> 16;
      acc0[2] += v.y & 0xFFFFu; acc0[3] += v.y >> 16;
      acc0[4] += v.z & 0xFFFFu; acc0[5] += v.z >> 16;
      acc0[6] += v.w & 0xFFFFu; acc0[7] += v.w >> 16;
    }
    int cc = c8 * 8;
    *(float4*)&sH[row][cc]     = make_float4((float)acc0[0], (float)acc0[1], (float)acc0[2], (float)acc0[3]);
    *(float4*)&sH[row][cc + 4] = make_float4((float)acc0[4], (float)acc0[5], (float)acc0[6], (float)acc0[7]);
  }
  // ---- K tile for j-chunk (64x64) ----
  int j0 = jq * 64;
#pragma unroll
  for (int rep = 0; rep < 4; rep++) {
    int idx = rep * 256 + tid;
    int jr = idx >> 4, g4 = (idx & 15) * 4;
    sK[jr][g4 + 0] = kval(j0 + jr, g4 + 0);
    sK[jr][g4 + 1] = kval(j0 + jr, g4 + 1);
    sK[jr][g4 + 2] = kval(j0 + jr, g4 + 2);
    sK[jr][g4 + 3] = kval(j0 + jr, g4 + 3);
  }
  __syncthreads();

  // ---- M-phase: acc[4] (1 i-row x 4 g) over 64 j ----
  float acc[4] = {0.f, 0.f, 0.f, 0.f};
#pragma unroll 4
  for (int tt = 0; tt < 16; tt++) {
    float4 hv = *(const float4*)&sH[row_i][tt * 4];
    float hh[4] = {hv.x, hv.y, hv.z, hv.w};
#pragma unroll
    for (int p = 0; p < 4; p++) {
      float4 v = *(const float4*)&sK[tt * 4 + p][gq4];
      acc[0] = fmaf(hh[p], v.x, acc[0]);
      acc[1] = fmaf(hh[p], v.y, acc[1]);
      acc[2] = fmaf(hh[p], v.z, acc[2]);
      acc[3] = fmaf(hh[p], v.w, acc[3]);
    }
  }
  __syncthreads();

  // ---- epilogue prep: M -> sH rows (16x64); K_C rows 0..15 -> sK ----
  *(float4*)&sH[row_i][gq4] = make_float4(acc[0], acc[1], acc[2], acc[3]);
  int i0f = it * 64 + qh * 16;
#pragma unroll
  for (int rep = 0; rep < 4; rep++) {           // 1024 = 16 rows x 64 r
    int idx = rep * 256 + tid;
    int ip = idx >> 6, r = idx & 63;
    sK[ip][r] = kval(i0f + ip, r);
  }
  __syncthreads();

  // ---- epilogue: P_quarter = K_C^T * M (on-chip) ----
  const int r4q = (tid >> 4) * 4;
  float acc2[4][4];
#pragma unroll
  for (int a = 0; a < 4; a++)
#pragma unroll
    for (int c = 0; c < 4; c++) acc2[a][c] = 0.0f;
#pragma unroll 4
  for (int ip = 0; ip < 16; ip++) {
    float4 kc = *(const float4*)&sK[ip][r4q];   // r-quad (broadcast in 16-lane groups)
    float4 mm = *(const float4*)&sH[ip][gq4];
    float kk2[4] = {kc.x, kc.y, kc.z, kc.w};
    float mv[4]  = {mm.x, mm.y, mm.z, mm.w};
#pragma unroll
    for (int dr = 0; dr < 4; dr++)
#pragma unroll
      for (int dg = 0; dg < 4; dg++)
        acc2[dr][dg] = fmaf(kk2[dr], mv[dg], acc2[dr][dg]);
  }

  // ---- slice sum (fixed order) + P write ----
  int sl2 = sl * 4 + qh;
  float ps = 0.0f;
#pragma unroll
  for (int dr = 0; dr < 4; dr++)
#pragma unroll
    for (int dg = 0; dg < 4; dg++) ps += acc2[dr][dg];
  sred[tid] = ps;
  __syncthreads();
  for (int st = 128; st > 0; st >>= 1) {
    if (tid < st) sred[tid] += sred[tid + st];
    __syncthreads();
  }
  if (tid == 0) psumC[b * NSLICE + sl2] = sred[0];

  float* Pb = Pp + ((size_t)b * NSLICE + sl2) * 4096;
#pragma unroll
  for (int dr = 0; dr < 4; dr++) {
    float4 v = make_float4(acc2[dr][0], acc2[dr][1], acc2[dr][2], acc2[dr][3]);
    *(float4*)&Pb[(size_t)(r4q + dr) * 64 + gq4] = v;
  }
}

// ---------------- K3: finalize — reduce 12 slices, normalize, store ----------------
__global__ __launch_bounds__(256) void finalize(const float* __restrict__ Pp,
                                                const float* __restrict__ psumC,
                                                float* __restrict__ out) {
  const int bid = blockIdx.x;        // 64 = b(16) x sl4(4); b&7 == bid&7 (XCD match)
  const int b = bid & 15;
  const int sl4 = bid >> 4;
  const int tid = threadIdx.x;
  const float* pc = psumC + b * NSLICE;
  float tot = 0.0f;
#pragma unroll
  for (int c = 0; c < NSLICE; c++) tot += pc[c];  // fixed order: deterministic
  float inv = 1.0f / (tot + EPS);
  int rg4 = sl4 * 1024 + tid * 4;
  const float* Pb = Pp + (size_t)b * NSLICE * 4096;
  float4 s = make_float4(0.f, 0.f, 0.f, 0.f);
#pragma unroll
  for (int c = 0; c < NSLICE; c++) {
    float4 v = *(const float4*)&Pb[(size_t)c * 4096 + rg4];
    s.x += v.x; s.y += v.y; s.z += v.z; s.w += v.w;
  }
  s.x *= inv; s.y *= inv; s.z *= inv; s.w *= inv;
  *(float4*)&out[(size_t)b * 4096 + rg4] = s;
}

extern "C" void kernel_launch(void* const* d_in, const int* in_sizes, int n_in,
                              void* d_out, int out_size, void* d_ws, size_t ws_size,
                              hipStream_t stream) {
  const float* x = (const float*)d_in[0];
  float* out = (float*)d_out;

  char* p = (char*)d_ws;
  unsigned int* Hq = (unsigned int*)p;  p += (size_t)BATCH * NCHUNK * SLAB4 * 16;  // 6.3 MB
  float* Pp = (float*)p;                p += (size_t)BATCH * NSLICE * 4096 * 4;    // 3.1 MB
  float* psumC = (float*)p;

  hist_full<<<256, 1024, 0, stream>>>(x, Hq);
  stageBC<<<192, 256, 0, stream>>>(Hq, Pp, psumC);
  finalize<<<64, 256, 0, stream>>>(Pp, psumC, out);
}